// Round 9
// baseline (372.906 us; speedup 1.0000x reference)
//
#include <hip/hip_runtime.h>
#include <math.h>

#define L_LEN 4500
#define KSPL 12   // K-splits for corr_k
#define KT 128    // corr K-tile (elements)
#define TW 148    // corr LDS row stride in words
#define NTB 18    // ceil(4500/256) (outconv tiling)
#define TLC 128   // conv12 l-tile
#define NTC 36    // ceil(4500/128)
#define CBLK 512  // conv12 blocks: 2 kh-sets x 256 (2 blocks/CU, 79.5 KB LDS each)
#define RS 72     // conv LDS plane row stride (f16 units); 16B-chunk stride 9 (odd) -> conflict-free b128

typedef _Float16 half8 __attribute__((ext_vector_type(8)));
typedef float f32x16 __attribute__((ext_vector_type(16)));

__device__ __forceinline__ half8 mk_half8(unsigned int w0, unsigned int w1,
                                          unsigned int w2, unsigned int w3) {
    union { unsigned int u[4]; half8 h; } t;
    t.u[0] = w0; t.u[1] = w1; t.u[2] = w2; t.u[3] = w3;
    return t.h;
}
__device__ __forceinline__ half8 u4_half8(uint4 v) {
    union { uint4 u; half8 h; } t; t.u = v; return t.h;
}

#define LOPAIR(a, b) (((a) & 0xffffu) | ((b) << 16))
#define HIPAIR(a, b) (((a) >> 16) | ((b) & 0xffff0000u))

// ------- prep: pack conv2 weights into MFMA A-fragment hi/lo u32 tables ------
// Also zero-inits rowsum (conv12 accumulates it atomically). sq comes free
// from the autocorrelation diagonal R[a][a][d=2].
__global__ void prep_w2f_k(const float* __restrict__ w2,
                           unsigned int* __restrict__ w2fh,
                           unsigned int* __restrict__ w2fl,
                           float* __restrict__ rowsum) {
    int i = blockIdx.x * 256 + threadIdx.x;
    if (i < 4096) rowsum[i] = 0.f;
    if (i >= 10240) return;
    int w = i & 3;
    int t = i >> 2;
    int lane = t & 63; t >>= 6;
    int ks = t & 3; t >>= 2;          // t now 0..9
    int g = t % 5;
    int kh = t / 5;
    int k = kh * 32 + (lane & 31);
    int ci0 = ks * 16 + (lane >> 5) * 8 + w * 2;
    unsigned int hw = 0, lw = 0;
#pragma unroll
    for (int e = 0; e < 2; ++e) {
        float v = w2[(k * 64 + ci0 + e) * 5 + g];
        _Float16 hi = (_Float16)v;
        _Float16 lo = (_Float16)(v - (float)hi);
        unsigned short hb = __builtin_bit_cast(unsigned short, hi);
        unsigned short lb = __builtin_bit_cast(unsigned short, lo);
        hw |= ((unsigned int)hb) << (16 * e);
        lw |= ((unsigned int)lb) << (16 * e);
    }
    w2fh[i] = hw;
    w2fl[i] = lw;
}

// ---- conv12_k (MFMA): fused conv1(k=7) + conv2(k=5), f16 hi/lo 3-split ------
// v5 (kh-split + LDS table): r8 proved the LDS-table loop is clean (FETCH
// 40MB->1.2MB) but its 120.5 KB footprint capped occupancy at 1 block/CU =
// 1 wave/SIMD (Occupancy 10%) -> every ds_read/MFMA dependency stall fully
// exposed, 129us. Fix: each block handles ONE kh half (32 k-outs), so the
// weight table halves to 40 KB and total LDS = 79.5 KB -> 2 blocks/CU ->
// 8 waves/CU (2/SIMD) of latency hiding. Wave = one 32x32 output tile;
// accumulator split into even/odd-step chains to cover dependent-MFMA
// latency at 2 waves/SIMD. Same n->XCD mapping (256%8==0 keeps both kh
// blocks of an n on one XCD) so h2 stays L2-local for corr_k.
__global__ __launch_bounds__(256, 2) void conv12_k(const float* __restrict__ x,
                                                   const float* __restrict__ w1,
                                                   const unsigned int* __restrict__ w2fh,
                                                   const unsigned int* __restrict__ w2fl,
                                                   float* __restrict__ h2,
                                                   float* __restrict__ rowsum) {
    __shared__ float xs[140];
    __shared__ __align__(16) _Float16 shh[132 * RS];
    __shared__ __align__(16) _Float16 shl[132 * RS];
    __shared__ __align__(16) uint4 wt[2560];   // 40,960 B: this block's kh half
    int lane = threadIdx.x & 63;
    int wid = threadIdx.x >> 6;    // wave = l-quadrant (32 cols each)
    int col = lane & 31;
    int kg = lane >> 5;
    int kh = blockIdx.x >> 8;      // blocks 0..255 -> kh=0, 256..511 -> kh=1
    int inner = blockIdx.x & 255;
    int xcd = inner & 7;
    int slot = inner >> 3;         // 0..31
    // ---- one-time table stage: 2560 coalesced uint4 (40 KB) ----
    {
        const uint4* WH = (const uint4*)w2fh + kh * 1280;
        const uint4* WL = (const uint4*)w2fl + kh * 1280;
        for (int i = threadIdx.x; i < 2560; i += 256)
            wt[i] = (i < 1280) ? WH[i] : WL[i - 1280];
    }
    // ---- per-lane conv1 weights (7 VGPRs) ----
    float w1r[7];
#pragma unroll
    for (int g = 0; g < 7; ++g) w1r[g] = w1[lane * 7 + g];
    const uint4* wa_h = &wt[lane];
    const uint4* wa_l = &wt[1280 + lane];

    for (int q2 = 0; q2 < 9; ++q2) {
        int j = xcd * 288 + slot + q2 * 32;    // (n,t) job; n in [xcd*8, xcd*8+8)
        int n = j / NTC;
        int t = j - n * NTC;
        int l0 = t * TLC;
        __syncthreads();                       // prev tile readers done; wt staged
        const float* xr = x + (size_t)n * L_LEN;
        if (threadIdx.x < 138) {
            int l = l0 - 5 + threadIdx.x;
            xs[threadIdx.x] = (l >= 0 && l < L_LEN) ? xr[l] : 0.f;
        }
        __syncthreads();
        {
            for (int tt = 0; tt < 33; ++tt) {
                int r = wid * 33 + tt;         // 132 rows over 4 waves
                int l = l0 + r - 2;
                float a = 0.f;
                if (l >= 0 && l < L_LEN) {
#pragma unroll
                    for (int g = 0; g < 7; ++g) a += w1r[g] * xs[r + g];
                }
                _Float16 hi = (_Float16)a;
                _Float16 lo = (_Float16)(a - (float)hi);
                shh[r * RS + lane] = hi;
                shl[r * RS + lane] = lo;
            }
        }
        __syncthreads();
        f32x16 accA, accB;
#pragma unroll
        for (int i = 0; i < 16; ++i) { accA[i] = 0.f; accB[i] = 0.f; }
#pragma unroll
        for (int g = 0; g < 5; ++g) {
#pragma unroll
            for (int ks = 0; ks < 4; ++ks) {
                int q = g * 4 + ks;
                int off = ks * 16 + kg * 8;
                half8 Ah = u4_half8(wa_h[q * 64]);
                half8 Al = u4_half8(wa_l[q * 64]);
                int rb = wid * 32 + col + g;
                half8 bh = *(const half8*)&shh[rb * RS + off];
                half8 bl = *(const half8*)&shl[rb * RS + off];
                if (q & 1) {
                    accB = __builtin_amdgcn_mfma_f32_32x32x16_f16(Al, bh, accB, 0, 0, 0);
                    accB = __builtin_amdgcn_mfma_f32_32x32x16_f16(Ah, bl, accB, 0, 0, 0);
                    accB = __builtin_amdgcn_mfma_f32_32x32x16_f16(Ah, bh, accB, 0, 0, 0);
                } else {
                    accA = __builtin_amdgcn_mfma_f32_32x32x16_f16(Al, bh, accA, 0, 0, 0);
                    accA = __builtin_amdgcn_mfma_f32_32x32x16_f16(Ah, bl, accA, 0, 0, 0);
                    accA = __builtin_amdgcn_mfma_f32_32x32x16_f16(Ah, bh, accA, 0, 0, 0);
                }
            }
        }
#pragma unroll
        for (int i = 0; i < 16; ++i) accA[i] += accB[i];
        int lcol = l0 + wid * 32 + col;
        if (lcol < L_LEN) {
#pragma unroll
            for (int rg = 0; rg < 16; ++rg) {
                int k = kh * 32 + (rg & 3) + 8 * (rg >> 2) + 4 * kg;
                h2[((size_t)n * 64 + k) * L_LEN + lcol] = accA[rg];
            }
        }
        // ---- fused rowsum: per rg reduce this wave's 32 l-cols ----
#pragma unroll
        for (int rg = 0; rg < 16; ++rg) {
            float s1 = (lcol < L_LEN) ? accA[rg] : 0.f;
#pragma unroll
            for (int m = 16; m; m >>= 1) s1 += __shfl_xor(s1, m, 32);
            if (col == 0) {
                int k = kh * 32 + (rg & 3) + 8 * (rg >> 2) + 4 * kg;
                atomicAdd(&rowsum[n * 64 + k], s1);
            }
        }
    }
}

// ---- corr_k (MFMA): R[a][b][d] = sum_l h2[a][l] * h2[b][l+d-2]  (OOB=0) -----
__global__ __launch_bounds__(256, 3) void corr_k(const float* __restrict__ h2,
                                                 float* __restrict__ Rp) {
    __shared__ __align__(16) unsigned int hl[64 * TW];   // 37,888 B
    int bid = blockIdx.x;
    int xcd = bid & 7;
    int r8 = bid >> 3;            // 0..95
    int n = xcd * 8 + (r8 & 7);   // all 12 splits of n share an XCD
    int s = r8 >> 3;              // 0..11
    const float* h2n = h2 + (size_t)n * 64 * L_LEN;

    int lane = threadIdx.x & 63;
    int wid = threadIdx.x >> 6;
    int a0 = (wid >> 1) * 32;
    int b0 = (wid & 1) * 32;
    int row31 = lane & 31;
    int g = lane >> 5;

    f32x16 acc[5];
#pragma unroll
    for (int d = 0; d < 5; ++d)
#pragma unroll
        for (int i = 0; i < 16; ++i) acc[d][i] = 0.f;

    int trow = threadIdx.x >> 2;   // staging row 0..63
    int tc4 = threadIdx.x & 3;     // staging chunk phase

    const unsigned int* arow = &hl[(a0 + row31) * TW + (g << 3)];
    const unsigned int* brow = &hl[(b0 + row31) * TW + (g << 3)];

    for (int tt = 0; tt < 3; ++tt) {
        int t = s + tt * KSPL;     // tile 0..35
        int l0 = t * KT;
        __syncthreads();           // protect previous tile's readers
        for (int i = 0; i < 9; ++i) {
            int c = tc4 + (i << 2);            // chunk 0..35
            int lbase = l0 - 8 + (c << 2);
            float v[4];
            if (lbase >= 0 && lbase + 3 < L_LEN) {
                float4 f = *(const float4*)(h2n + (size_t)trow * L_LEN + lbase);
                v[0] = f.x; v[1] = f.y; v[2] = f.z; v[3] = f.w;
            } else {
#pragma unroll
                for (int q = 0; q < 4; ++q) {
                    int l = lbase + q;
                    v[q] = (l >= 0 && l < L_LEN) ? h2n[(size_t)trow * L_LEN + l] : 0.f;
                }
            }
            unsigned int wv[4];
#pragma unroll
            for (int q = 0; q < 4; ++q) {
                float xv = v[q];
                _Float16 hi = (_Float16)xv;
                float hif = (float)hi;
                _Float16 lo = (_Float16)(xv - hif);
                unsigned short hb = __builtin_bit_cast(unsigned short, hi);
                unsigned short lb = __builtin_bit_cast(unsigned short, lo);
                wv[q] = (unsigned int)hb | ((unsigned int)lb << 16);
            }
            uint4 uu; uu.x = wv[0]; uu.y = wv[1]; uu.z = wv[2]; uu.w = wv[3];
            *(uint4*)&hl[trow * TW + (c << 2)] = uu;
        }
        __syncthreads();
#pragma unroll
        for (int ks = 0; ks < 8; ++ks) {
            const int u0 = 8 + ks * 16;
            uint4 va0 = *(const uint4*)(arow + u0);
            uint4 va1 = *(const uint4*)(arow + u0 + 4);
            uint4 vb0 = *(const uint4*)(brow + u0 - 4);
            uint4 vb1 = *(const uint4*)(brow + u0);
            uint4 vb2 = *(const uint4*)(brow + u0 + 4);
            uint4 vb3 = *(const uint4*)(brow + u0 + 8);
            unsigned int WA[8] = {va0.x, va0.y, va0.z, va0.w, va1.x, va1.y, va1.z, va1.w};
            unsigned int V[16] = {vb0.x, vb0.y, vb0.z, vb0.w, vb1.x, vb1.y, vb1.z, vb1.w,
                                  vb2.x, vb2.y, vb2.z, vb2.w, vb3.x, vb3.y, vb3.z, vb3.w};
            half8 Ahi = mk_half8(LOPAIR(WA[0], WA[1]), LOPAIR(WA[2], WA[3]),
                                 LOPAIR(WA[4], WA[5]), LOPAIR(WA[6], WA[7]));
            half8 Alo = mk_half8(HIPAIR(WA[0], WA[1]), HIPAIR(WA[2], WA[3]),
                                 HIPAIR(WA[4], WA[5]), HIPAIR(WA[6], WA[7]));
#pragma unroll
            for (int d = 0; d < 5; ++d) {
                half8 Bhi = mk_half8(LOPAIR(V[d + 2], V[d + 3]), LOPAIR(V[d + 4], V[d + 5]),
                                     LOPAIR(V[d + 6], V[d + 7]), LOPAIR(V[d + 8], V[d + 9]));
                half8 Blo = mk_half8(HIPAIR(V[d + 2], V[d + 3]), HIPAIR(V[d + 4], V[d + 5]),
                                     HIPAIR(V[d + 6], V[d + 7]), HIPAIR(V[d + 8], V[d + 9]));
                acc[d] = __builtin_amdgcn_mfma_f32_32x32x16_f16(Alo, Bhi, acc[d], 0, 0, 0);
                acc[d] = __builtin_amdgcn_mfma_f32_32x32x16_f16(Ahi, Blo, acc[d], 0, 0, 0);
                acc[d] = __builtin_amdgcn_mfma_f32_32x32x16_f16(Ahi, Bhi, acc[d], 0, 0, 0);
            }
        }
    }
    float* base = Rp + (size_t)(n * KSPL + s) * 20480;
#pragma unroll
    for (int d = 0; d < 5; ++d) {
#pragma unroll
        for (int rg = 0; rg < 16; ++rg) {
            int crow = (rg & 3) + 8 * (rg >> 2) + 4 * g;
            base[d * 4096 + (a0 + crow) * 64 + b0 + row31] = acc[d][rg];
        }
    }
}

// -- redT_k: sum the KSPL partials AND transpose [d][a][b] -> [a][b][d] -------
__global__ __launch_bounds__(256) void redT_k(const float* __restrict__ Rp,
                                              float* __restrict__ Rsum2) {
    __shared__ float ldsA[1280];
    int n = blockIdx.x >> 4;
    int a0 = (blockIdx.x & 15) * 4;
    int tid = threadIdx.x;
    float sacc[5];
#pragma unroll
    for (int q = 0; q < 5; ++q) sacc[q] = 0.f;
    for (int s2 = 0; s2 < KSPL; ++s2) {
        const float* src = Rp + (size_t)(n * KSPL + s2) * 20480;
#pragma unroll
        for (int q = 0; q < 5; ++q) {
            int idx2 = q * 256 + tid;          // 0..1279
            int aL = idx2 / 320;
            int r = idx2 - 320 * aL;
            int d = r >> 6;
            int bb = r & 63;
            sacc[q] += src[d * 4096 + (a0 + aL) * 64 + bb];
        }
    }
#pragma unroll
    for (int q = 0; q < 5; ++q) ldsA[q * 256 + tid] = sacc[q];
    __syncthreads();
    float* dst = Rsum2 + (size_t)n * 20480 + a0 * 320;
#pragma unroll
    for (int q = 0; q < 5; ++q) {
        int oidx = q * 256 + tid;              // 0..1279 contiguous out
        int aL = oidx / 320;
        int rr = oidx - 320 * aL;
        int bb = rr / 5;
        int d = rr - 5 * bb;
        dst[oidx] = ldsA[aL * 320 + d * 64 + bb];
    }
}

// ---- mjk_k: M[n][c][ij] partial for one (i,j) pair -- grid 64n x 36(ij) -----
__global__ __launch_bounds__(256) void mjk_k(const float* __restrict__ Rsum2,
                                             const float* __restrict__ h2,
                                             const float* __restrict__ wA,
                                             float* __restrict__ Mout) {
    __shared__ float Rsub[320];
    __shared__ float wsA[1536];
    __shared__ float s0a[8], s1a[8], inva[8], s0b[8], s1b[8], invb[8];
    __shared__ float Mp[256];
    int bid = blockIdx.x;
    int n = bid / 36;
    int ij = bid - n * 36;
    int i = 0, rem = ij;
    while (rem >= 8 - i) { rem -= 8 - i; ++i; }
    int j = i + rem;
    int tid = threadIdx.x;
    size_t rbase = (size_t)n * 20480;
    {
        size_t base = rbase + (size_t)(8 * i) * 320 + (size_t)(8 * j) * 5;
        for (int fidx = tid; fidx < 320; fidx += 256)
            Rsub[fidx] = Rsum2[base + (fidx / 40) * 320 + (fidx % 40)];
    }
    for (int q = tid; q < 1536; q += 256) wsA[q] = wA[q];
    if (tid < 8) {
        int a = 8 * i + tid;
        s0a[tid] = h2[((size_t)n * 64 + a) * L_LEN + 0];
        s1a[tid] = h2[((size_t)n * 64 + a) * L_LEN + (L_LEN - 1)];
        inva[tid] = 1.f / (1.f + Rsum2[rbase + a * 325 + 2]);
    } else if (tid < 16) {
        int b = 8 * j + (tid - 8);
        s0b[tid - 8] = h2[((size_t)n * 64 + b) * L_LEN + 0];
        s1b[tid - 8] = h2[((size_t)n * 64 + b) * L_LEN + (L_LEN - 1)];
        invb[tid - 8] = 1.f / (1.f + Rsum2[rbase + b * 325 + 2]);
    }
    __syncthreads();
    int c = tid & 63;
    int sub = tid >> 6;
    float acc = 0.f;
#pragma unroll
    for (int pl = 0; pl < 2; ++pl) {
        int p = sub * 2 + pl;
        float ia = inva[p];
        float w0 = wsA[c * 24 + p * 3], w1 = wsA[c * 24 + p * 3 + 1],
              w2v = wsA[c * 24 + p * 3 + 2];
        float e1a = s1a[p], e0a = s0a[p];
#pragma unroll
        for (int pp = 0; pp < 8; ++pp) {
            float q0 = wsA[c * 24 + pp * 3], q1 = wsA[c * 24 + pp * 3 + 1],
                  q2 = wsA[c * 24 + pp * 3 + 2];
            const float* R5 = &Rsub[(p * 8 + pp) * 5];
            float term = (w2v * q0) * R5[0]
                       + (w1 * q0 + w2v * q1) * R5[1]
                       + (w0 * q0 + w1 * q1 + w2v * q2) * R5[2]
                       + (w0 * q1 + w1 * q2) * R5[3]
                       + (w0 * q2) * R5[4]
                       - (w0 * q0) * (e1a * s1b[pp])
                       - (w2v * q2) * (e0a * s0b[pp]);
            acc += ia * invb[pp] * term;
        }
    }
    Mp[tid] = acc;
    __syncthreads();
    if (tid < 64)
        Mout[((size_t)n * 64 + tid) * 36 + ij] =
            Mp[tid] + Mp[tid + 64] + Mp[tid + 128] + Mp[tid + 192];
}

// ---- routing_k: bias/SG terms + the per-(n,c) softmax routing tail ----------
__global__ __launch_bounds__(64) void routing_k(const float* __restrict__ Mout,
                                                const float* __restrict__ Rsum2,
                                                const float* __restrict__ h2,
                                                const float* __restrict__ rowsum,
                                                const float* __restrict__ wA,
                                                const float* __restrict__ bA,
                                                float* __restrict__ coefb) {
    __shared__ float s0s[64], s1s[64], Ts[64], invs[64];
    int n = blockIdx.x;
    int c = threadIdx.x;
    {
        int a = c;
        s0s[a] = h2[((size_t)n * 64 + a) * L_LEN + 0];
        s1s[a] = h2[((size_t)n * 64 + a) * L_LEN + (L_LEN - 1)];
        Ts[a]  = rowsum[n * 64 + a];
        invs[a] = 1.f / (1.f + Rsum2[(size_t)n * 20480 + a * 325 + 2]);
    }
    __syncthreads();
    float wreg[24];
#pragma unroll
    for (int q = 0; q < 24; ++q) wreg[q] = wA[c * 24 + q];
    float bc = bA[c];
    float SG[8];
#pragma unroll
    for (int i = 0; i < 8; ++i) {
        float s = 0.f;
#pragma unroll
        for (int p = 0; p < 8; ++p) {
            int a = 8 * i + p;
            float Ta = Ts[a];
            s += invs[a] * (wreg[p * 3 + 0] * (Ta - s1s[a]) +
                            wreg[p * 3 + 1] * Ta +
                            wreg[p * 3 + 2] * (Ta - s0s[a]));
        }
        SG[i] = s;
    }
    const float* Mrow = Mout + ((size_t)n * 64 + c) * 36;
    float M[36];
    {
        int k2 = 0;
#pragma unroll
        for (int i = 0; i < 8; ++i)
#pragma unroll
            for (int j = i; j < 8; ++j, ++k2)
                M[k2] = Mrow[k2] + bc * (SG[i] + SG[j]) + 4500.f * bc * bc;
    }
    float rs[8];
#pragma unroll
    for (int i = 0; i < 8; ++i) rs[i] = 0.f;
    {
        int idx2 = 0;
#pragma unroll
        for (int i = 0; i < 8; ++i)
#pragma unroll
            for (int j = i; j < 8; ++j, ++idx2) {
                rs[i] += M[idx2];
                if (j > i) rs[j] += M[idx2];
            }
    }
    float sumAll = 0.f;
#pragma unroll
    for (int i = 0; i < 8; ++i) sumAll += rs[i];
    float sqn1 = sumAll * (1.f / 64.f);
    float binv = 1.f / (8.f * (1.f + sqn1));
    float bv[8], mx = -1e30f;
#pragma unroll
    for (int i = 0; i < 8; ++i) { bv[i] = rs[i] * binv; mx = fmaxf(mx, bv[i]); }
    float e[8], se = 0.f;
#pragma unroll
    for (int i = 0; i < 8; ++i) { e[i] = expf(bv[i] - mx); se += e[i]; }
    float sinv = 1.f / se;
    float ci_[8];
#pragma unroll
    for (int i = 0; i < 8; ++i) ci_[i] = e[i] * sinv;
    float sqn2 = 0.f;
    {
        int idx2 = 0;
#pragma unroll
        for (int i = 0; i < 8; ++i)
#pragma unroll
            for (int j = i; j < 8; ++j, ++idx2)
                sqn2 += ((j > i) ? 2.f : 1.f) * ci_[i] * ci_[j] * M[idx2];
    }
    float scale = 1.f / (1.f + sqn2);
#pragma unroll
    for (int i = 0; i < 8; ++i) coefb[((size_t)n * 64 + c) * 8 + i] = ci_[i] * scale;
}

// -------- weff_k: emit Weff directly as MFMA A-fragment hi/lo tables ---------
__global__ __launch_bounds__(256) void weff_k(const float* __restrict__ coefb,
                                              const float* __restrict__ wA,
                                              const float* __restrict__ Rsum2,
                                              const float* __restrict__ bA,
                                              unsigned int* __restrict__ Wfh,
                                              unsigned int* __restrict__ Wfl,
                                              float* __restrict__ vbias) {
    __shared__ float invs[64];
    __shared__ float coefs[512];
    int n = blockIdx.x;
    if (threadIdx.x < 64)
        invs[threadIdx.x] =
            1.f / (1.f + Rsum2[(size_t)n * 20480 + threadIdx.x * 325 + 2]);
    for (int i = threadIdx.x; i < 512; i += 256) coefs[i] = coefb[(size_t)n * 512 + i];
    __syncthreads();
    for (int i = threadIdx.x; i < 6144; i += 256) {
        int w = i & 3;
        int t2 = i >> 2;
        int lane = t2 & 63; t2 >>= 6;
        int ks = t2 & 3; t2 >>= 2;     // t2 now 0..5
        int g = t2 % 3;
        int kh = t2 / 3;
        int k = kh * 32 + (lane & 31);
        int ci0 = ks * 16 + (lane >> 5) * 8 + w * 2;
        unsigned int hw = 0, lw = 0;
#pragma unroll
        for (int e = 0; e < 2; ++e) {
            int ci = ci0 + e;
            float v = coefs[k * 8 + (ci >> 3)] * wA[k * 24 + (ci & 7) * 3 + g] *
                      invs[ci] * 65536.f;
            _Float16 hi = (_Float16)v;
            _Float16 lo = (_Float16)(v - (float)hi);
            unsigned short hb = __builtin_bit_cast(unsigned short, hi);
            unsigned short lb = __builtin_bit_cast(unsigned short, lo);
            hw |= ((unsigned int)hb) << (16 * e);
            lw |= ((unsigned int)lb) << (16 * e);
        }
        Wfh[(size_t)n * 6144 + i] = hw;
        Wfl[(size_t)n * 6144 + i] = lw;
    }
    if (threadIdx.x < 64) {
        float s = 0.f;
#pragma unroll
        for (int i = 0; i < 8; ++i) s += coefb[((size_t)n * 64 + threadIdx.x) * 8 + i];
        vbias[n * 64 + threadIdx.x] = bA[threadIdx.x] * s;
    }
}

// ---- outconv_k (MFMA): out = Weff (64->64, k=3) * h2 + vbias ----------------
__global__ __launch_bounds__(256, 2) void outconv_k(const float* __restrict__ h2,
                                                    const unsigned int* __restrict__ Wfh,
                                                    const unsigned int* __restrict__ Wfl,
                                                    const float* __restrict__ vbias,
                                                    float* __restrict__ out) {
    __shared__ __align__(16) _Float16 shh[264 * RS];
    __shared__ __align__(16) _Float16 shl[264 * RS];
    __shared__ float vbs[64];
    int b = blockIdx.x;
    int xcd = b & 7;
    int gi = xcd * 144 + (b >> 3);
    int n = gi / NTB;
    int t = gi - n * NTB;
    int l0 = t * 256;
    const float* h2n = h2 + (size_t)n * 64 * L_LEN;
    if (threadIdx.x < 64) vbs[threadIdx.x] = vbias[n * 64 + threadIdx.x];
    {
        int trow = threadIdx.x >> 2;       // h2 row (ci) 0..63
        int tc4 = threadIdx.x & 3;         // chunk phase
        const float* hrow = h2n + (size_t)trow * L_LEN;
        int lb = l0 - 4;
        for (int i = 0; i < 17; ++i) {
            int c = tc4 + 4 * i;
            if (c >= 66) break;
            int lbase = lb + 4 * c;
            float v[4];
            if (lbase >= 0 && lbase + 3 < L_LEN) {
                float4 f = *(const float4*)(hrow + lbase);
                v[0] = f.x; v[1] = f.y; v[2] = f.z; v[3] = f.w;
            } else {
#pragma unroll
                for (int q = 0; q < 4; ++q) {
                    int l = lbase + q;
                    v[q] = (l >= 0 && l < L_LEN) ? hrow[l] : 0.f;
                }
            }
            int r = 4 * c;
#pragma unroll
            for (int q = 0; q < 4; ++q) {
                _Float16 hi = (_Float16)v[q];
                _Float16 lo = (_Float16)(v[q] - (float)hi);
                shh[(r + q) * RS + trow] = hi;
                shl[(r + q) * RS + trow] = lo;
            }
        }
    }
    __syncthreads();
    int lane = threadIdx.x & 63;
    int wid = threadIdx.x >> 6;
    int col = lane & 31;
    int kg = lane >> 5;
    int lb0 = wid * 64 + col;
    f32x16 acc[2][2];
#pragma unroll
    for (int a1 = 0; a1 < 2; ++a1)
#pragma unroll
        for (int a2 = 0; a2 < 2; ++a2)
#pragma unroll
            for (int i = 0; i < 16; ++i) acc[a1][a2][i] = 0.f;
    const uint4* WH = (const uint4*)(Wfh + (size_t)n * 6144);
    const uint4* WL = (const uint4*)(Wfl + (size_t)n * 6144);
#pragma unroll
    for (int g = 0; g < 3; ++g) {
#pragma unroll
        for (int ks = 0; ks < 4; ++ks) {
            uint4 ah0 = WH[((0 * 3 + g) * 4 + ks) * 64 + lane];
            uint4 ah1 = WH[((1 * 3 + g) * 4 + ks) * 64 + lane];
            uint4 al0 = WL[((0 * 3 + g) * 4 + ks) * 64 + lane];
            uint4 al1 = WL[((1 * 3 + g) * 4 + ks) * 64 + lane];
            int off = ks * 16 + kg * 8;
            int rb = lb0 + g + 3;
            half8 bh0 = *(const half8*)&shh[rb * RS + off];
            half8 bl0 = *(const half8*)&shl[rb * RS + off];
            half8 bh1 = *(const half8*)&shh[(rb + 32) * RS + off];
            half8 bl1 = *(const half8*)&shl[(rb + 32) * RS + off];
            half8 Ah0 = u4_half8(ah0), Al0 = u4_half8(al0);
            half8 Ah1 = u4_half8(ah1), Al1 = u4_half8(al1);
            acc[0][0] = __builtin_amdgcn_mfma_f32_32x32x16_f16(Al0, bh0, acc[0][0], 0, 0, 0);
            acc[0][0] = __builtin_amdgcn_mfma_f32_32x32x16_f16(Ah0, bl0, acc[0][0], 0, 0, 0);
            acc[0][0] = __builtin_amdgcn_mfma_f32_32x32x16_f16(Ah0, bh0, acc[0][0], 0, 0, 0);
            acc[0][1] = __builtin_amdgcn_mfma_f32_32x32x16_f16(Al0, bh1, acc[0][1], 0, 0, 0);
            acc[0][1] = __builtin_amdgcn_mfma_f32_32x32x16_f16(Ah0, bl1, acc[0][1], 0, 0, 0);
            acc[0][1] = __builtin_amdgcn_mfma_f32_32x32x16_f16(Ah0, bh1, acc[0][1], 0, 0, 0);
            acc[1][0] = __builtin_amdgcn_mfma_f32_32x32x16_f16(Al1, bh0, acc[1][0], 0, 0, 0);
            acc[1][0] = __builtin_amdgcn_mfma_f32_32x32x16_f16(Ah1, bl0, acc[1][0], 0, 0, 0);
            acc[1][0] = __builtin_amdgcn_mfma_f32_32x32x16_f16(Ah1, bh0, acc[1][0], 0, 0, 0);
            acc[1][1] = __builtin_amdgcn_mfma_f32_32x32x16_f16(Al1, bh1, acc[1][1], 0, 0, 0);
            acc[1][1] = __builtin_amdgcn_mfma_f32_32x32x16_f16(Ah1, bl1, acc[1][1], 0, 0, 0);
            acc[1][1] = __builtin_amdgcn_mfma_f32_32x32x16_f16(Ah1, bh1, acc[1][1], 0, 0, 0);
        }
    }
    const float inv_scale = 1.f / 65536.f;
#pragma unroll
    for (int kh = 0; kh < 2; ++kh) {
#pragma unroll
        for (int ls = 0; ls < 2; ++ls) {
            int lcol = l0 + lb0 + ls * 32;
            if (lcol < L_LEN) {
#pragma unroll
                for (int rg = 0; rg < 16; ++rg) {
                    int k = kh * 32 + (rg & 3) + 8 * (rg >> 2) + 4 * kg;
                    out[((size_t)n * 64 + k) * L_LEN + lcol] =
                        acc[kh][ls][rg] * inv_scale + vbs[k];
                }
            }
        }
    }
}

extern "C" void kernel_launch(void* const* d_in, const int* in_sizes, int n_in,
                              void* d_out, int out_size, void* d_ws, size_t ws_size,
                              hipStream_t stream) {
    const float* x  = (const float*)d_in[0];
    const float* w1 = (const float*)d_in[1];
    const float* w2 = (const float*)d_in[2];
    const float* wA = (const float*)d_in[3];
    const float* bA = (const float*)d_in[4];
    float* out = (float*)d_out;
    char* ws = (char*)d_ws;
    const size_t HB = (size_t)64 * 64 * L_LEN * 4;   // 73,728,000 B
    float* h2     = (float*)(ws + HB);
    float* rowsum = (float*)(ws + 2 * HB + 16384);    // 16 KB
    unsigned int* w2fh = (unsigned int*)(ws + 2 * HB + 32768);   // 40 KB
    unsigned int* w2fl = (unsigned int*)(ws + 2 * HB + 32768 + 40960); // 40 KB
    // overlays in the first HB region:
    float* Rp    = (float*)ws;                        // 62,914,560 B
    float* Rsum2 = (float*)(ws + 62914560);           //  5,242,880 B
    float* coefb = (float*)(ws + 68157440);           //    131,072 B
    unsigned int* Wfh = (unsigned int*)(ws + 68288512);           // 1,572,864 B
    unsigned int* Wfl = (unsigned int*)(ws + 68288512 + 1572864); // 1,572,864 B
    float* vbias = (float*)(ws + 71434240);           //     16,384 B
    float* Mout  = (float*)(ws + 71450624);           //    589,824 B

    prep_w2f_k<<<40, 256, 0, stream>>>(w2, w2fh, w2fl, rowsum);
    conv12_k<<<CBLK, 256, 0, stream>>>(x, w1, w2fh, w2fl, h2, rowsum);
    corr_k<<<64 * KSPL, 256, 0, stream>>>(h2, Rp);
    redT_k<<<64 * 16, 256, 0, stream>>>(Rp, Rsum2);
    mjk_k<<<64 * 36, 256, 0, stream>>>(Rsum2, h2, wA, Mout);
    routing_k<<<64, 64, 0, stream>>>(Mout, Rsum2, h2, rowsum, wA, bA, coefb);
    weff_k<<<64, 256, 0, stream>>>(coefb, wA, Rsum2, bA, Wfh, Wfl, vbias);
    outconv_k<<<64 * NTB, 256, 0, stream>>>(h2, Wfh, Wfl, vbias, out);
}

// Round 11
// 264.315 us; speedup vs baseline: 1.4108x; 1.4108x over previous
//
#include <hip/hip_runtime.h>
#include <math.h>

#define L_LEN 4500
#define KSPL 12   // K-splits for corr_k
#define KT 128    // corr K-tile (elements)
#define TW 148    // corr LDS row stride in words
#define NTB 18    // ceil(4500/256)
#define RS 72     // outconv LDS plane row stride

typedef _Float16 half8 __attribute__((ext_vector_type(8)));
typedef float f32x16 __attribute__((ext_vector_type(16)));

__device__ __forceinline__ half8 mk_half8(unsigned int w0, unsigned int w1,
                                          unsigned int w2, unsigned int w3) {
    union { unsigned int u[4]; half8 h; } t;
    t.u[0] = w0; t.u[1] = w1; t.u[2] = w2; t.u[3] = w3;
    return t.h;
}
__device__ __forceinline__ half8 u4_half8(uint4 v) {
    union { uint4 u; half8 h; } t; t.u = v; return t.h;
}

#define LOPAIR(a, b) (((a) & 0xffffu) | ((b) << 16))
#define HIPAIR(a, b) (((a) >> 16) | ((b) & 0xffff0000u))

// -- prep_weq_k: collapse conv1(k=7,1ch) o conv2(k=5) into one 11-tap conv ----
// Weq[k][d] = sum_ci sum_{g1+g2=d} w1[ci][g1] * w2[k][ci][g2].  Exact except
// at l in {0,1,L-2,L-1} (conv2 taps h1 outside [0,L)); bnd_k subtracts those.
__global__ __launch_bounds__(64) void prep_weq_k(const float* __restrict__ w1,
                                                 const float* __restrict__ w2,
                                                 float* __restrict__ Weq) {
    __shared__ float w1s[448];
    __shared__ float part[11 * 64];
    int k = blockIdx.x;
    int ci = threadIdx.x;
#pragma unroll
    for (int g = 0; g < 7; ++g) w1s[ci * 7 + g] = w1[ci * 7 + g];
    __syncthreads();
    float acc[11];
#pragma unroll
    for (int d = 0; d < 11; ++d) acc[d] = 0.f;
#pragma unroll
    for (int g2 = 0; g2 < 5; ++g2) {
        float wv = w2[(k * 64 + ci) * 5 + g2];
#pragma unroll
        for (int g1 = 0; g1 < 7; ++g1) acc[g2 + g1] += wv * w1s[ci * 7 + g1];
    }
#pragma unroll
    for (int d = 0; d < 11; ++d) part[d * 64 + ci] = acc[d];
    __syncthreads();
    if (ci < 11) {
        float s = 0.f;
#pragma unroll
        for (int q = 0; q < 64; ++q) s += part[ci * 64 + q];
        Weq[k * 11 + ci] = s;
    }
}

// -- conv12s_k: h2[k][l] = sum_d Weq[k][d] * xpad[l+d-5] -- pure f32 stream ---
// Replaces 5 rounds of MFMA conv12 variants (best 116us, all latency-bound,
// every pipe <20%): the 1-input-channel structure makes the 64->64 GEMM
// algebraically collapse to 0.4 GFLOP. Memory-bound on the 74 MB h2 write.
__global__ __launch_bounds__(256) void conv12s_k(const float* __restrict__ x,
                                                 const float* __restrict__ Weq,
                                                 float* __restrict__ h2) {
    __shared__ float xs[266];
    int b = blockIdx.x;
    int xcd = b & 7;
    int gi = xcd * 144 + (b >> 3);    // n-contiguous per XCD (h2 L2-local for corr)
    int n = gi / NTB;
    int t = gi - n * NTB;
    int l0 = t * 256;
    const float* xr = x + (size_t)n * L_LEN;
    for (int idx = threadIdx.x; idx < 266; idx += 256) {
        int l = l0 - 5 + idx;
        xs[idx] = (l >= 0 && l < L_LEN) ? xr[l] : 0.f;
    }
    __syncthreads();
    int l = l0 + threadIdx.x;
    if (l >= L_LEN) return;
    float xv[11];
#pragma unroll
    for (int d = 0; d < 11; ++d) xv[d] = xs[threadIdx.x + d];
    float* h2n = h2 + (size_t)n * 64 * L_LEN + l;
#pragma unroll
    for (int k = 0; k < 64; ++k) {
        float a = 0.f;
#pragma unroll
        for (int d = 0; d < 11; ++d) a += Weq[k * 11 + d] * xv[d];   // uniform -> s_load
        h2n[(size_t)k * L_LEN] = a;
    }
}

// -- bnd_k: subtract the h1-truncation terms at l in {0,1,L-2,L-1}, and write
// rowsum analytically: sum_l composed = sum_d Weq[k][d]*S_x(d), minus corr.
__global__ __launch_bounds__(64) void bnd_k(const float* __restrict__ x,
                                            const float* __restrict__ w1,
                                            const float* __restrict__ w2,
                                            const float* __restrict__ Weq,
                                            float* __restrict__ h2,
                                            float* __restrict__ rowsum) {
    __shared__ float hvm2[64], hvm1[64], hvL[64], hvL1[64];
    int n = blockIdx.x;
    int tid = threadIdx.x;           // one wave
    const float* xr = x + (size_t)n * L_LEN;
    // X_total (wave reduce over 64 lanes)
    float s = 0.f;
    for (int i = tid; i < L_LEN; i += 64) s += xr[i];
#pragma unroll
    for (int m = 32; m; m >>= 1) s += __shfl_xor(s, m);
    float X_total = s;
    float x0 = xr[0], x1 = xr[1], x2 = xr[2];
    float xm3 = xr[L_LEN - 3], xm2 = xr[L_LEN - 2], xm1 = xr[L_LEN - 1];
    // h1virt at l' = -2,-1,L,L+1 for ci = tid
    {
        const float* wr = w1 + tid * 7;
        hvm2[tid] = wr[5] * x0 + wr[6] * x1;
        hvm1[tid] = wr[4] * x0 + wr[5] * x1 + wr[6] * x2;
        hvL[tid]  = wr[0] * xm3 + wr[1] * xm2 + wr[2] * xm1;
        hvL1[tid] = wr[0] * xm2 + wr[1] * xm1;
    }
    __syncthreads();
    int k = tid;
    float c0 = 0.f, c1 = 0.f, cL2 = 0.f, cL1 = 0.f;
    for (int ci = 0; ci < 64; ++ci) {
        const float* wp = w2 + (k * 64 + ci) * 5;
        c0  += wp[0] * hvm2[ci] + wp[1] * hvm1[ci];
        c1  += wp[0] * hvm1[ci];
        cL2 += wp[4] * hvL[ci];
        cL1 += wp[3] * hvL[ci] + wp[4] * hvL1[ci];
    }
    float* h2row = h2 + ((size_t)n * 64 + k) * L_LEN;
    h2row[0]         -= c0;
    h2row[1]         -= c1;
    h2row[L_LEN - 2] -= cL2;
    h2row[L_LEN - 1] -= cL1;
    // rowsum = sum_d Weq[k][d]*S_x(d) - (c0+c1+cL2+cL1)
    float head[6], tail[6];
    head[0] = 0.f; tail[0] = 0.f;
#pragma unroll
    for (int j = 1; j <= 5; ++j) {
        head[j] = head[j - 1] + xr[j - 1];
        tail[j] = tail[j - 1] + xr[L_LEN - j];
    }
    float rs = 0.f;
#pragma unroll
    for (int d = 0; d < 11; ++d) {
        float Sx = X_total - ((d < 5) ? tail[5 - d] : (d > 5) ? head[d - 5] : 0.f);
        rs += Weq[k * 11 + d] * Sx;
    }
    rowsum[n * 64 + k] = rs - (c0 + c1 + cL2 + cL1);
}

// ---- corr_k (MFMA): R[a][b][d] = sum_l h2[a][l] * h2[b][l+d-2]  (OOB=0) -----
__global__ __launch_bounds__(256, 3) void corr_k(const float* __restrict__ h2,
                                                 float* __restrict__ Rp) {
    __shared__ __align__(16) unsigned int hl[64 * TW];   // 37,888 B
    int bid = blockIdx.x;
    int xcd = bid & 7;
    int r8 = bid >> 3;            // 0..95
    int n = xcd * 8 + (r8 & 7);   // all 12 splits of n share an XCD
    int s = r8 >> 3;              // 0..11
    const float* h2n = h2 + (size_t)n * 64 * L_LEN;

    int lane = threadIdx.x & 63;
    int wid = threadIdx.x >> 6;
    int a0 = (wid >> 1) * 32;
    int b0 = (wid & 1) * 32;
    int row31 = lane & 31;
    int g = lane >> 5;

    f32x16 acc[5];
#pragma unroll
    for (int d = 0; d < 5; ++d)
#pragma unroll
        for (int i = 0; i < 16; ++i) acc[d][i] = 0.f;

    int trow = threadIdx.x >> 2;   // staging row 0..63
    int tc4 = threadIdx.x & 3;     // staging chunk phase

    const unsigned int* arow = &hl[(a0 + row31) * TW + (g << 3)];
    const unsigned int* brow = &hl[(b0 + row31) * TW + (g << 3)];

    for (int tt = 0; tt < 3; ++tt) {
        int t = s + tt * KSPL;     // tile 0..35
        int l0 = t * KT;
        __syncthreads();           // protect previous tile's readers
        for (int i = 0; i < 9; ++i) {
            int c = tc4 + (i << 2);            // chunk 0..35
            int lbase = l0 - 8 + (c << 2);
            float v[4];
            if (lbase >= 0 && lbase + 3 < L_LEN) {
                float4 f = *(const float4*)(h2n + (size_t)trow * L_LEN + lbase);
                v[0] = f.x; v[1] = f.y; v[2] = f.z; v[3] = f.w;
            } else {
#pragma unroll
                for (int q = 0; q < 4; ++q) {
                    int l = lbase + q;
                    v[q] = (l >= 0 && l < L_LEN) ? h2n[(size_t)trow * L_LEN + l] : 0.f;
                }
            }
            unsigned int wv[4];
#pragma unroll
            for (int q = 0; q < 4; ++q) {
                float xv = v[q];
                _Float16 hi = (_Float16)xv;
                float hif = (float)hi;
                _Float16 lo = (_Float16)(xv - hif);
                unsigned short hb = __builtin_bit_cast(unsigned short, hi);
                unsigned short lb = __builtin_bit_cast(unsigned short, lo);
                wv[q] = (unsigned int)hb | ((unsigned int)lb << 16);
            }
            uint4 uu; uu.x = wv[0]; uu.y = wv[1]; uu.z = wv[2]; uu.w = wv[3];
            *(uint4*)&hl[trow * TW + (c << 2)] = uu;
        }
        __syncthreads();
#pragma unroll
        for (int ks = 0; ks < 8; ++ks) {
            const int u0 = 8 + ks * 16;
            uint4 va0 = *(const uint4*)(arow + u0);
            uint4 va1 = *(const uint4*)(arow + u0 + 4);
            uint4 vb0 = *(const uint4*)(brow + u0 - 4);
            uint4 vb1 = *(const uint4*)(brow + u0);
            uint4 vb2 = *(const uint4*)(brow + u0 + 4);
            uint4 vb3 = *(const uint4*)(brow + u0 + 8);
            unsigned int WA[8] = {va0.x, va0.y, va0.z, va0.w, va1.x, va1.y, va1.z, va1.w};
            unsigned int V[16] = {vb0.x, vb0.y, vb0.z, vb0.w, vb1.x, vb1.y, vb1.z, vb1.w,
                                  vb2.x, vb2.y, vb2.z, vb2.w, vb3.x, vb3.y, vb3.z, vb3.w};
            half8 Ahi = mk_half8(LOPAIR(WA[0], WA[1]), LOPAIR(WA[2], WA[3]),
                                 LOPAIR(WA[4], WA[5]), LOPAIR(WA[6], WA[7]));
            half8 Alo = mk_half8(HIPAIR(WA[0], WA[1]), HIPAIR(WA[2], WA[3]),
                                 HIPAIR(WA[4], WA[5]), HIPAIR(WA[6], WA[7]));
#pragma unroll
            for (int d = 0; d < 5; ++d) {
                half8 Bhi = mk_half8(LOPAIR(V[d + 2], V[d + 3]), LOPAIR(V[d + 4], V[d + 5]),
                                     LOPAIR(V[d + 6], V[d + 7]), LOPAIR(V[d + 8], V[d + 9]));
                half8 Blo = mk_half8(HIPAIR(V[d + 2], V[d + 3]), HIPAIR(V[d + 4], V[d + 5]),
                                     HIPAIR(V[d + 6], V[d + 7]), HIPAIR(V[d + 8], V[d + 9]));
                acc[d] = __builtin_amdgcn_mfma_f32_32x32x16_f16(Alo, Bhi, acc[d], 0, 0, 0);
                acc[d] = __builtin_amdgcn_mfma_f32_32x32x16_f16(Ahi, Blo, acc[d], 0, 0, 0);
                acc[d] = __builtin_amdgcn_mfma_f32_32x32x16_f16(Ahi, Bhi, acc[d], 0, 0, 0);
            }
        }
    }
    float* base = Rp + (size_t)(n * KSPL + s) * 20480;
#pragma unroll
    for (int d = 0; d < 5; ++d) {
#pragma unroll
        for (int rg = 0; rg < 16; ++rg) {
            int crow = (rg & 3) + 8 * (rg >> 2) + 4 * g;
            base[d * 4096 + (a0 + crow) * 64 + b0 + row31] = acc[d][rg];
        }
    }
}

// -- redT_k: sum the KSPL partials AND transpose [d][a][b] -> [a][b][d] -------
__global__ __launch_bounds__(256) void redT_k(const float* __restrict__ Rp,
                                              float* __restrict__ Rsum2) {
    __shared__ float ldsA[1280];
    int n = blockIdx.x >> 4;
    int a0 = (blockIdx.x & 15) * 4;
    int tid = threadIdx.x;
    float sacc[5];
#pragma unroll
    for (int q = 0; q < 5; ++q) sacc[q] = 0.f;
    for (int s2 = 0; s2 < KSPL; ++s2) {
        const float* src = Rp + (size_t)(n * KSPL + s2) * 20480;
#pragma unroll
        for (int q = 0; q < 5; ++q) {
            int idx2 = q * 256 + tid;          // 0..1279
            int aL = idx2 / 320;
            int r = idx2 - 320 * aL;
            int d = r >> 6;
            int bb = r & 63;
            sacc[q] += src[d * 4096 + (a0 + aL) * 64 + bb];
        }
    }
#pragma unroll
    for (int q = 0; q < 5; ++q) ldsA[q * 256 + tid] = sacc[q];
    __syncthreads();
    float* dst = Rsum2 + (size_t)n * 20480 + a0 * 320;
#pragma unroll
    for (int q = 0; q < 5; ++q) {
        int oidx = q * 256 + tid;              // 0..1279 contiguous out
        int aL = oidx / 320;
        int rr = oidx - 320 * aL;
        int bb = rr / 5;
        int d = rr - 5 * bb;
        dst[oidx] = ldsA[aL * 320 + d * 64 + bb];
    }
}

// ---- mjk_k: M[n][c][ij] partial for one (i,j) pair -- grid 64n x 36(ij) -----
__global__ __launch_bounds__(256) void mjk_k(const float* __restrict__ Rsum2,
                                             const float* __restrict__ h2,
                                             const float* __restrict__ wA,
                                             float* __restrict__ Mout) {
    __shared__ float Rsub[320];
    __shared__ float wsA[1536];
    __shared__ float s0a[8], s1a[8], inva[8], s0b[8], s1b[8], invb[8];
    __shared__ float Mp[256];
    int bid = blockIdx.x;
    int n = bid / 36;
    int ij = bid - n * 36;
    int i = 0, rem = ij;
    while (rem >= 8 - i) { rem -= 8 - i; ++i; }
    int j = i + rem;
    int tid = threadIdx.x;
    size_t rbase = (size_t)n * 20480;
    {
        size_t base = rbase + (size_t)(8 * i) * 320 + (size_t)(8 * j) * 5;
        for (int fidx = tid; fidx < 320; fidx += 256)
            Rsub[fidx] = Rsum2[base + (fidx / 40) * 320 + (fidx % 40)];
    }
    for (int q = tid; q < 1536; q += 256) wsA[q] = wA[q];
    if (tid < 8) {
        int a = 8 * i + tid;
        s0a[tid] = h2[((size_t)n * 64 + a) * L_LEN + 0];
        s1a[tid] = h2[((size_t)n * 64 + a) * L_LEN + (L_LEN - 1)];
        inva[tid] = 1.f / (1.f + Rsum2[rbase + a * 325 + 2]);
    } else if (tid < 16) {
        int b = 8 * j + (tid - 8);
        s0b[tid - 8] = h2[((size_t)n * 64 + b) * L_LEN + 0];
        s1b[tid - 8] = h2[((size_t)n * 64 + b) * L_LEN + (L_LEN - 1)];
        invb[tid - 8] = 1.f / (1.f + Rsum2[rbase + b * 325 + 2]);
    }
    __syncthreads();
    int c = tid & 63;
    int sub = tid >> 6;
    float acc = 0.f;
#pragma unroll
    for (int pl = 0; pl < 2; ++pl) {
        int p = sub * 2 + pl;
        float ia = inva[p];
        float w0 = wsA[c * 24 + p * 3], w1 = wsA[c * 24 + p * 3 + 1],
              w2v = wsA[c * 24 + p * 3 + 2];
        float e1a = s1a[p], e0a = s0a[p];
#pragma unroll
        for (int pp = 0; pp < 8; ++pp) {
            float q0 = wsA[c * 24 + pp * 3], q1 = wsA[c * 24 + pp * 3 + 1],
                  q2 = wsA[c * 24 + pp * 3 + 2];
            const float* R5 = &Rsub[(p * 8 + pp) * 5];
            float term = (w2v * q0) * R5[0]
                       + (w1 * q0 + w2v * q1) * R5[1]
                       + (w0 * q0 + w1 * q1 + w2v * q2) * R5[2]
                       + (w0 * q1 + w1 * q2) * R5[3]
                       + (w0 * q2) * R5[4]
                       - (w0 * q0) * (e1a * s1b[pp])
                       - (w2v * q2) * (e0a * s0b[pp]);
            acc += ia * invb[pp] * term;
        }
    }
    Mp[tid] = acc;
    __syncthreads();
    if (tid < 64)
        Mout[((size_t)n * 64 + tid) * 36 + ij] =
            Mp[tid] + Mp[tid + 64] + Mp[tid + 128] + Mp[tid + 192];
}

// ---- routing_k: bias/SG terms + the per-(n,c) softmax routing tail ----------
__global__ __launch_bounds__(64) void routing_k(const float* __restrict__ Mout,
                                                const float* __restrict__ Rsum2,
                                                const float* __restrict__ h2,
                                                const float* __restrict__ rowsum,
                                                const float* __restrict__ wA,
                                                const float* __restrict__ bA,
                                                float* __restrict__ coefb) {
    __shared__ float s0s[64], s1s[64], Ts[64], invs[64];
    int n = blockIdx.x;
    int c = threadIdx.x;
    {
        int a = c;
        s0s[a] = h2[((size_t)n * 64 + a) * L_LEN + 0];
        s1s[a] = h2[((size_t)n * 64 + a) * L_LEN + (L_LEN - 1)];
        Ts[a]  = rowsum[n * 64 + a];
        invs[a] = 1.f / (1.f + Rsum2[(size_t)n * 20480 + a * 325 + 2]);
    }
    __syncthreads();
    float wreg[24];
#pragma unroll
    for (int q = 0; q < 24; ++q) wreg[q] = wA[c * 24 + q];
    float bc = bA[c];
    float SG[8];
#pragma unroll
    for (int i = 0; i < 8; ++i) {
        float s = 0.f;
#pragma unroll
        for (int p = 0; p < 8; ++p) {
            int a = 8 * i + p;
            float Ta = Ts[a];
            s += invs[a] * (wreg[p * 3 + 0] * (Ta - s1s[a]) +
                            wreg[p * 3 + 1] * Ta +
                            wreg[p * 3 + 2] * (Ta - s0s[a]));
        }
        SG[i] = s;
    }
    const float* Mrow = Mout + ((size_t)n * 64 + c) * 36;
    float M[36];
    {
        int k2 = 0;
#pragma unroll
        for (int i = 0; i < 8; ++i)
#pragma unroll
            for (int j = i; j < 8; ++j, ++k2)
                M[k2] = Mrow[k2] + bc * (SG[i] + SG[j]) + 4500.f * bc * bc;
    }
    float rs[8];
#pragma unroll
    for (int i = 0; i < 8; ++i) rs[i] = 0.f;
    {
        int idx2 = 0;
#pragma unroll
        for (int i = 0; i < 8; ++i)
#pragma unroll
            for (int j = i; j < 8; ++j, ++idx2) {
                rs[i] += M[idx2];
                if (j > i) rs[j] += M[idx2];
            }
    }
    float sumAll = 0.f;
#pragma unroll
    for (int i = 0; i < 8; ++i) sumAll += rs[i];
    float sqn1 = sumAll * (1.f / 64.f);
    float binv = 1.f / (8.f * (1.f + sqn1));
    float bv[8], mx = -1e30f;
#pragma unroll
    for (int i = 0; i < 8; ++i) { bv[i] = rs[i] * binv; mx = fmaxf(mx, bv[i]); }
    float e[8], se = 0.f;
#pragma unroll
    for (int i = 0; i < 8; ++i) { e[i] = expf(bv[i] - mx); se += e[i]; }
    float sinv = 1.f / se;
    float ci_[8];
#pragma unroll
    for (int i = 0; i < 8; ++i) ci_[i] = e[i] * sinv;
    float sqn2 = 0.f;
    {
        int idx2 = 0;
#pragma unroll
        for (int i = 0; i < 8; ++i)
#pragma unroll
            for (int j = i; j < 8; ++j, ++idx2)
                sqn2 += ((j > i) ? 2.f : 1.f) * ci_[i] * ci_[j] * M[idx2];
    }
    float scale = 1.f / (1.f + sqn2);
#pragma unroll
    for (int i = 0; i < 8; ++i) coefb[((size_t)n * 64 + c) * 8 + i] = ci_[i] * scale;
}

// -------- weff_k: emit Weff directly as MFMA A-fragment hi/lo tables ---------
__global__ __launch_bounds__(256) void weff_k(const float* __restrict__ coefb,
                                              const float* __restrict__ wA,
                                              const float* __restrict__ Rsum2,
                                              const float* __restrict__ bA,
                                              unsigned int* __restrict__ Wfh,
                                              unsigned int* __restrict__ Wfl,
                                              float* __restrict__ vbias) {
    __shared__ float invs[64];
    __shared__ float coefs[512];
    int n = blockIdx.x;
    if (threadIdx.x < 64)
        invs[threadIdx.x] =
            1.f / (1.f + Rsum2[(size_t)n * 20480 + threadIdx.x * 325 + 2]);
    for (int i = threadIdx.x; i < 512; i += 256) coefs[i] = coefb[(size_t)n * 512 + i];
    __syncthreads();
    for (int i = threadIdx.x; i < 6144; i += 256) {
        int w = i & 3;
        int t2 = i >> 2;
        int lane = t2 & 63; t2 >>= 6;
        int ks = t2 & 3; t2 >>= 2;     // t2 now 0..5
        int g = t2 % 3;
        int kh = t2 / 3;
        int k = kh * 32 + (lane & 31);
        int ci0 = ks * 16 + (lane >> 5) * 8 + w * 2;
        unsigned int hw = 0, lw = 0;
#pragma unroll
        for (int e = 0; e < 2; ++e) {
            int ci = ci0 + e;
            float v = coefs[k * 8 + (ci >> 3)] * wA[k * 24 + (ci & 7) * 3 + g] *
                      invs[ci] * 65536.f;
            _Float16 hi = (_Float16)v;
            _Float16 lo = (_Float16)(v - (float)hi);
            unsigned short hb = __builtin_bit_cast(unsigned short, hi);
            unsigned short lb = __builtin_bit_cast(unsigned short, lo);
            hw |= ((unsigned int)hb) << (16 * e);
            lw |= ((unsigned int)lb) << (16 * e);
        }
        Wfh[(size_t)n * 6144 + i] = hw;
        Wfl[(size_t)n * 6144 + i] = lw;
    }
    if (threadIdx.x < 64) {
        float s = 0.f;
#pragma unroll
        for (int i = 0; i < 8; ++i) s += coefb[((size_t)n * 64 + threadIdx.x) * 8 + i];
        vbias[n * 64 + threadIdx.x] = bA[threadIdx.x] * s;
    }
}

// ---- outconv_k (MFMA): out = Weff (64->64, k=3) * h2 + vbias ----------------
__global__ __launch_bounds__(256, 2) void outconv_k(const float* __restrict__ h2,
                                                    const unsigned int* __restrict__ Wfh,
                                                    const unsigned int* __restrict__ Wfl,
                                                    const float* __restrict__ vbias,
                                                    float* __restrict__ out) {
    __shared__ __align__(16) _Float16 shh[264 * RS];
    __shared__ __align__(16) _Float16 shl[264 * RS];
    __shared__ float vbs[64];
    int b = blockIdx.x;
    int xcd = b & 7;
    int gi = xcd * 144 + (b >> 3);
    int n = gi / NTB;
    int t = gi - n * NTB;
    int l0 = t * 256;
    const float* h2n = h2 + (size_t)n * 64 * L_LEN;
    if (threadIdx.x < 64) vbs[threadIdx.x] = vbias[n * 64 + threadIdx.x];
    {
        int trow = threadIdx.x >> 2;       // h2 row (ci) 0..63
        int tc4 = threadIdx.x & 3;         // chunk phase
        const float* hrow = h2n + (size_t)trow * L_LEN;
        int lb = l0 - 4;
        for (int i = 0; i < 17; ++i) {
            int c = tc4 + 4 * i;
            if (c >= 66) break;
            int lbase = lb + 4 * c;
            float v[4];
            if (lbase >= 0 && lbase + 3 < L_LEN) {
                float4 f = *(const float4*)(hrow + lbase);
                v[0] = f.x; v[1] = f.y; v[2] = f.z; v[3] = f.w;
            } else {
#pragma unroll
                for (int q = 0; q < 4; ++q) {
                    int l = lbase + q;
                    v[q] = (l >= 0 && l < L_LEN) ? hrow[l] : 0.f;
                }
            }
            int r = 4 * c;
#pragma unroll
            for (int q = 0; q < 4; ++q) {
                _Float16 hi = (_Float16)v[q];
                _Float16 lo = (_Float16)(v[q] - (float)hi);
                shh[(r + q) * RS + trow] = hi;
                shl[(r + q) * RS + trow] = lo;
            }
        }
    }
    __syncthreads();
    int lane = threadIdx.x & 63;
    int wid = threadIdx.x >> 6;
    int col = lane & 31;
    int kg = lane >> 5;
    int lb0 = wid * 64 + col;
    f32x16 acc[2][2];
#pragma unroll
    for (int a1 = 0; a1 < 2; ++a1)
#pragma unroll
        for (int a2 = 0; a2 < 2; ++a2)
#pragma unroll
            for (int i = 0; i < 16; ++i) acc[a1][a2][i] = 0.f;
    const uint4* WH = (const uint4*)(Wfh + (size_t)n * 6144);
    const uint4* WL = (const uint4*)(Wfl + (size_t)n * 6144);
#pragma unroll
    for (int g = 0; g < 3; ++g) {
#pragma unroll
        for (int ks = 0; ks < 4; ++ks) {
            uint4 ah0 = WH[((0 * 3 + g) * 4 + ks) * 64 + lane];
            uint4 ah1 = WH[((1 * 3 + g) * 4 + ks) * 64 + lane];
            uint4 al0 = WL[((0 * 3 + g) * 4 + ks) * 64 + lane];
            uint4 al1 = WL[((1 * 3 + g) * 4 + ks) * 64 + lane];
            int off = ks * 16 + kg * 8;
            int rb = lb0 + g + 3;
            half8 bh0 = *(const half8*)&shh[rb * RS + off];
            half8 bl0 = *(const half8*)&shl[rb * RS + off];
            half8 bh1 = *(const half8*)&shh[(rb + 32) * RS + off];
            half8 bl1 = *(const half8*)&shl[(rb + 32) * RS + off];
            half8 Ah0 = u4_half8(ah0), Al0 = u4_half8(al0);
            half8 Ah1 = u4_half8(ah1), Al1 = u4_half8(al1);
            acc[0][0] = __builtin_amdgcn_mfma_f32_32x32x16_f16(Al0, bh0, acc[0][0], 0, 0, 0);
            acc[0][0] = __builtin_amdgcn_mfma_f32_32x32x16_f16(Ah0, bl0, acc[0][0], 0, 0, 0);
            acc[0][0] = __builtin_amdgcn_mfma_f32_32x32x16_f16(Ah0, bh0, acc[0][0], 0, 0, 0);
            acc[0][1] = __builtin_amdgcn_mfma_f32_32x32x16_f16(Al0, bh1, acc[0][1], 0, 0, 0);
            acc[0][1] = __builtin_amdgcn_mfma_f32_32x32x16_f16(Ah0, bl1, acc[0][1], 0, 0, 0);
            acc[0][1] = __builtin_amdgcn_mfma_f32_32x32x16_f16(Ah0, bh1, acc[0][1], 0, 0, 0);
            acc[1][0] = __builtin_amdgcn_mfma_f32_32x32x16_f16(Al1, bh0, acc[1][0], 0, 0, 0);
            acc[1][0] = __builtin_amdgcn_mfma_f32_32x32x16_f16(Ah1, bl0, acc[1][0], 0, 0, 0);
            acc[1][0] = __builtin_amdgcn_mfma_f32_32x32x16_f16(Ah1, bh0, acc[1][0], 0, 0, 0);
            acc[1][1] = __builtin_amdgcn_mfma_f32_32x32x16_f16(Al1, bh1, acc[1][1], 0, 0, 0);
            acc[1][1] = __builtin_amdgcn_mfma_f32_32x32x16_f16(Ah1, bl1, acc[1][1], 0, 0, 0);
            acc[1][1] = __builtin_amdgcn_mfma_f32_32x32x16_f16(Ah1, bh1, acc[1][1], 0, 0, 0);
        }
    }
    const float inv_scale = 1.f / 65536.f;
#pragma unroll
    for (int kh = 0; kh < 2; ++kh) {
#pragma unroll
        for (int ls = 0; ls < 2; ++ls) {
            int lcol = l0 + lb0 + ls * 32;
            if (lcol < L_LEN) {
#pragma unroll
                for (int rg = 0; rg < 16; ++rg) {
                    int k = kh * 32 + (rg & 3) + 8 * (rg >> 2) + 4 * kg;
                    out[((size_t)n * 64 + k) * L_LEN + lcol] =
                        acc[kh][ls][rg] * inv_scale + vbs[k];
                }
            }
        }
    }
}

extern "C" void kernel_launch(void* const* d_in, const int* in_sizes, int n_in,
                              void* d_out, int out_size, void* d_ws, size_t ws_size,
                              hipStream_t stream) {
    const float* x  = (const float*)d_in[0];
    const float* w1 = (const float*)d_in[1];
    const float* w2 = (const float*)d_in[2];
    const float* wA = (const float*)d_in[3];
    const float* bA = (const float*)d_in[4];
    float* out = (float*)d_out;
    char* ws = (char*)d_ws;
    const size_t HB = (size_t)64 * 64 * L_LEN * 4;   // 73,728,000 B
    float* h2     = (float*)(ws + HB);
    float* rowsum = (float*)(ws + 2 * HB + 16384);    // 16 KB
    float* Weq    = (float*)(ws + 2 * HB + 32768);    // 2,816 B (64x11)
    // overlays in the first HB region:
    float* Rp    = (float*)ws;                        // 62,914,560 B
    float* Rsum2 = (float*)(ws + 62914560);           //  5,242,880 B
    float* coefb = (float*)(ws + 68157440);           //    131,072 B
    unsigned int* Wfh = (unsigned int*)(ws + 68288512);           // 1,572,864 B
    unsigned int* Wfl = (unsigned int*)(ws + 68288512 + 1572864); // 1,572,864 B
    float* vbias = (float*)(ws + 71434240);           //     16,384 B
    float* Mout  = (float*)(ws + 71450624);           //    589,824 B

    prep_weq_k<<<64, 64, 0, stream>>>(w1, w2, Weq);
    conv12s_k<<<64 * NTB, 256, 0, stream>>>(x, Weq, h2);
    bnd_k<<<64, 64, 0, stream>>>(x, w1, w2, Weq, h2, rowsum);
    corr_k<<<64 * KSPL, 256, 0, stream>>>(h2, Rp);
    redT_k<<<64 * 16, 256, 0, stream>>>(Rp, Rsum2);
    mjk_k<<<64 * 36, 256, 0, stream>>>(Rsum2, h2, wA, Mout);
    routing_k<<<64, 64, 0, stream>>>(Mout, Rsum2, h2, rowsum, wA, bA, coefb);
    weff_k<<<64, 256, 0, stream>>>(coefb, wA, Rsum2, bA, Wfh, Wfl, vbias);
    outconv_k<<<64 * NTB, 256, 0, stream>>>(h2, Wfh, Wfl, vbias, out);
}